// Round 12
// baseline (644.202 us; speedup 1.0000x reference)
//
#include <hip/hip_runtime.h>

#define NE   8
#define DIN  4096
#define DOUT 4096
#define TOK  8192

#define BM 128
#define BN 128
#define BKF 64    // fast-path K-step (bf16 elems)

// legacy fallback tile params
#define BK 32
#define LDSK 40

typedef __attribute__((ext_vector_type(4))) float f32x4;
typedef __attribute__((ext_vector_type(8))) short bf16x8;
typedef __attribute__((ext_vector_type(2))) unsigned long long u64x2;

#define AS1 __attribute__((address_space(1)))
#define AS3 __attribute__((address_space(3)))

static __device__ __forceinline__ unsigned short f2bf(float f) {
  unsigned u = __builtin_bit_cast(unsigned, f);
  u += 0x7fffu + ((u >> 16) & 1u);   // RTNE
  return (unsigned short)(u >> 16);
}

static __device__ __forceinline__ unsigned long long pack4(f32x4 v) {
  return (unsigned long long)f2bf(v[0])
       | ((unsigned long long)f2bf(v[1]) << 16)
       | ((unsigned long long)f2bf(v[2]) << 32)
       | ((unsigned long long)f2bf(v[3]) << 48);
}

static __device__ __forceinline__ void gload16(const void* g, void* l) {
  __builtin_amdgcn_global_load_lds((const AS1 unsigned int*)g,
                                   (AS3 unsigned int*)l, 16, 0, 0);
}

// ---------- fused prep: gating (fp32-exact) + x->bf16  AND  weights->bf16 ----------
// (round-7 proven version: cacheable loads; NT variant regressed in r11)
__global__ void prep_kernel(const float* __restrict__ x, const float* __restrict__ gw,
                            const float* __restrict__ gb, int* __restrict__ counts,
                            int* __restrict__ tlist, unsigned short* __restrict__ xbf,
                            const float* __restrict__ ew, unsigned short* __restrict__ wbf) {
  if (blockIdx.x < TOK / 4) {
    // ---- gating + x conversion (4 tokens/block, 1 wave/token) ----
    const int lane = threadIdx.x & 63;
    const int tok  = blockIdx.x * 4 + (threadIdx.x >> 6);
    const float* xr = x + (size_t)tok * DIN;
    unsigned short* xo = xbf + (size_t)tok * DIN;
    float acc[NE];
    #pragma unroll
    for (int e = 0; e < NE; ++e) acc[e] = 0.f;
    for (int i = lane * 4; i < DIN; i += 256) {
      f32x4 xv = *(const f32x4*)(xr + i);
      *(unsigned long long*)(xo + i) = pack4(xv);
      #pragma unroll
      for (int e = 0; e < NE; ++e) {
        f32x4 wv = *(const f32x4*)(gw + e * DIN + i);
        acc[e] += xv[0]*wv[0] + xv[1]*wv[1] + xv[2]*wv[2] + xv[3]*wv[3];
      }
    }
    #pragma unroll
    for (int e = 0; e < NE; ++e) {
      float v = acc[e];
      #pragma unroll
      for (int o = 32; o > 0; o >>= 1) v += __shfl_xor(v, o);
      acc[e] = v;
    }
    if (lane == 0) {
      float bv = acc[0] + gb[0];
      int best = 0;
      #pragma unroll
      for (int e = 1; e < NE; ++e) {
        float v = acc[e] + gb[e];
        if (v > bv) { bv = v; best = e; }   // strict > == numpy first-max
      }
      int pos = atomicAdd(&counts[best], 1);
      tlist[best * TOK + pos] = tok;
    }
  } else {
    // ---- expert weights fp32 -> bf16 (8192 blocks, grid-stride) ----
    const int bid = blockIdx.x - TOK / 4;
    const size_t n = (size_t)NE * DOUT * DIN;
    size_t idx = ((size_t)bid * 256 + threadIdx.x) * 8;
    const size_t stride = (size_t)8192 * 256 * 8;
    for (; idx < n; idx += stride) {
      f32x4 a = *(const f32x4*)(ew + idx);
      f32x4 b = *(const f32x4*)(ew + idx + 4);
      u64x2 v; v[0] = pack4(a); v[1] = pack4(b);
      *(u64x2*)(wbf + idx) = v;
    }
  }
}

// ---------- fast grouped GEMM (round-7 internals + XCD-chunked 1D grid) ----------
// 128x128, BK=64, single-buffer 2-barrier loop, global_load_lds width-16,
// pre-swizzled source: 341 us, MfmaUtil 37%, bank conflicts == 0.
// Grid: 2304 blocks = 8 XCDs x 288 (9 slots x 32 ntiles per XCD chunk):
// each XCD runs complete ntile-sweeps of its slots -> the slot's 1MB A-panel
// stays resident in that XCD's private L2 (T1, bijective, nwg%8==0).
__global__ __launch_bounds__(256, 2)
void moe_gemm_bf(const unsigned short* __restrict__ xbf,
                 const unsigned short* __restrict__ wbf,
                 const float* __restrict__ eb,
                 const int* __restrict__ counts,
                 const int* __restrict__ tlist,
                 float* __restrict__ out) {
  __shared__ unsigned short sA[BM * BKF];  // 16 KB, linear [128][64]
  __shared__ unsigned short sB[BN * BKF];  // 16 KB
  __shared__ int rowtok[BM];

  const int tid = threadIdx.x;

  // XCD-bijective chunked swizzle (1D grid, gridDim.x = 2304 = 8 * 288)
  const int cpx   = gridDim.x >> 3;                                  // 288
  const int wgid  = ((int)blockIdx.x & 7) * cpx + ((int)blockIdx.x >> 3);
  const int slot  = wgid >> 5;     // ntile varies fastest within a chunk
  const int ntile = wgid & 31;

  int e = -1, mtile = 0, Me = 0;
  {
    int acc = 0;
    #pragma unroll
    for (int j = 0; j < NE; ++j) {
      int c = counts[j];
      int t = (c + BM - 1) / BM;
      if (e < 0 && slot < acc + t) { e = j; mtile = slot - acc; Me = c; }
      acc += t;
    }
  }
  if (e < 0) return;

  const int n0 = ntile * BN;
  const int m0 = mtile * BM;

  if (tid < BM) {
    int r = m0 + tid;
    rowtok[tid] = tlist[e * TOK + (r < Me ? r : Me - 1)];
  }
  __syncthreads();

  const int lane = tid & 63;
  const int w    = tid >> 6;
  // staging geometry: each wave chunk c stages 8 rows x 64 cols (1 KB)
  const int j8   = lane & 7;     // 16B slot within row
  const int rsub = lane >> 3;    // row within 8-row chunk
  const int colsw = ((j8 ^ rsub) * 8);  // pre-swizzled global elem offset (T2 involution)

  const unsigned short* ag[4];
  const unsigned short* bg[4];
  const unsigned short* wbase = wbf + (size_t)e * DOUT * DIN;
  #pragma unroll
  for (int c = 0; c < 4; ++c) {
    int row = (w * 4 + c) * 8 + rsub;
    ag[c] = xbf   + (size_t)rowtok[row] * DIN + colsw;
    bg[c] = wbase + (size_t)(n0 + row)  * DIN + colsw;
  }

  const int wr = (w >> 1) * 64;
  const int wc = (w & 1) * 64;
  const int lr = lane & 15;
  const int lk = lane >> 4;
  const int lr7 = lr & 7;

  f32x4 acc[4][4];
  #pragma unroll
  for (int m = 0; m < 4; ++m)
    #pragma unroll
    for (int n = 0; n < 4; ++n) acc[m][n] = (f32x4){0.f, 0.f, 0.f, 0.f};

  for (int kt = 0; kt < DIN / BKF; ++kt) {   // 64 K-tiles
    const int kofs = kt * BKF;
    #pragma unroll
    for (int c = 0; c < 4; ++c) {
      gload16(ag[c] + kofs, &sA[(w * 4 + c) * 512]);
      gload16(bg[c] + kofs, &sB[(w * 4 + c) * 512]);
    }
    __syncthreads();   // drains vmcnt before barrier (compiler-inserted)

    #pragma unroll
    for (int ks = 0; ks < 2; ++ks) {
      bf16x8 af[4], bfv[4];
      #pragma unroll
      for (int m = 0; m < 4; ++m)
        af[m] = *(const bf16x8*)&sA[(wr + m * 16 + lr) * BKF + (((ks * 4 + lk) ^ lr7) * 8)];
      #pragma unroll
      for (int n = 0; n < 4; ++n)
        bfv[n] = *(const bf16x8*)&sB[(wc + n * 16 + lr) * BKF + (((ks * 4 + lk) ^ lr7) * 8)];
      #pragma unroll
      for (int m = 0; m < 4; ++m)
        #pragma unroll
        for (int n = 0; n < 4; ++n)
          acc[m][n] = __builtin_amdgcn_mfma_f32_16x16x32_bf16(af[m], bfv[n], acc[m][n], 0, 0, 0);
    }
    __syncthreads();
  }

  // epilogue: bias + guarded scatter (C/D: col = lane&15, row = (lane>>4)*4 + j)
  float bias[4];
  #pragma unroll
  for (int n = 0; n < 4; ++n) bias[n] = eb[e * DOUT + n0 + wc + n * 16 + lr];

  #pragma unroll
  for (int m = 0; m < 4; ++m) {
    #pragma unroll
    for (int j = 0; j < 4; ++j) {
      int rloc = wr + m * 16 + lk * 4 + j;
      if (m0 + rloc < Me) {
        int tokr = rowtok[rloc];
        float* op = out + (size_t)tokr * DOUT + n0 + wc;
        #pragma unroll
        for (int n = 0; n < 4; ++n)
          op[n * 16 + lr] = acc[m][n][j] + bias[n];
      }
    }
  }
}

// ================= legacy fallback path (used only if ws too small) ==========
__global__ void gate_kernel(const float* __restrict__ x, const float* __restrict__ gw,
                            const float* __restrict__ gb, int* __restrict__ counts,
                            int* __restrict__ tlist) {
  const int lane = threadIdx.x & 63;
  const int tok  = blockIdx.x * 4 + (threadIdx.x >> 6);
  const float* xr = x + (size_t)tok * DIN;
  float acc[NE];
  #pragma unroll
  for (int e = 0; e < NE; ++e) acc[e] = 0.f;
  for (int i = lane; i < DIN; i += 64) {
    float xv = xr[i];
    #pragma unroll
    for (int e = 0; e < NE; ++e) acc[e] += xv * gw[e * DIN + i];
  }
  #pragma unroll
  for (int e = 0; e < NE; ++e) {
    float v = acc[e];
    #pragma unroll
    for (int o = 32; o > 0; o >>= 1) v += __shfl_xor(v, o);
    acc[e] = v;
  }
  if (lane == 0) {
    float bv = acc[0] + gb[0];
    int best = 0;
    #pragma unroll
    for (int e = 1; e < NE; ++e) {
      float v = acc[e] + gb[e];
      if (v > bv) { bv = v; best = e; }
    }
    int pos = atomicAdd(&counts[best], 1);
    tlist[best * TOK + pos] = tok;
  }
}

__global__ __launch_bounds__(256, 2)
void moe_gemm(const float* __restrict__ x, const float* __restrict__ ew,
              const float* __restrict__ eb, const int* __restrict__ counts,
              const int* __restrict__ tlist, float* __restrict__ out) {
  __shared__ unsigned short fA[2][BM * LDSK];
  __shared__ unsigned short fB[2][BM * LDSK];
  __shared__ int rowtok[BM];

  const int tid  = threadIdx.x;
  const int slot = blockIdx.y;

  int e = -1, mtile = 0, Me = 0;
  {
    int acc = 0;
    #pragma unroll
    for (int j = 0; j < NE; ++j) {
      int c = counts[j];
      int t = (c + BM - 1) / BM;
      if (e < 0 && slot < acc + t) { e = j; mtile = slot - acc; Me = c; }
      acc += t;
    }
  }
  if (e < 0) return;

  const int n0 = blockIdx.x * BM;
  const int m0 = mtile * BM;
  const float* we = ew + (size_t)e * DOUT * DIN;

  if (tid < BM) {
    int r = m0 + tid;
    rowtok[tid] = tlist[e * TOK + (r < Me ? r : Me - 1)];
  }
  __syncthreads();

  const int srow = tid >> 3;
  const int scol = (tid & 7) * 4;
  const int lane = tid & 63;
  const int w  = tid >> 6;
  const int wr = (w >> 1) * 64;
  const int wc = (w & 1) * 64;
  const int lr = lane & 15;
  const int lk = lane >> 4;

  f32x4 accf[4][4];
  #pragma unroll
  for (int m = 0; m < 4; ++m)
    #pragma unroll
    for (int n = 0; n < 4; ++n) accf[m][n] = (f32x4){0.f, 0.f, 0.f, 0.f};

  const float* aptr[4];
  const float* bptr[4];
  #pragma unroll
  for (int p = 0; p < 4; ++p) {
    int r = p * 32 + srow;
    aptr[p] = x  + (size_t)rowtok[r] * DIN + scol;
    bptr[p] = we + (size_t)(n0 + r)  * DIN + scol;
  }

  #pragma unroll
  for (int p = 0; p < 4; ++p) {
    int r = p * 32 + srow;
    *(unsigned long long*)&fA[0][r * LDSK + scol] = pack4(*(const f32x4*)(aptr[p]));
    *(unsigned long long*)&fB[0][r * LDSK + scol] = pack4(*(const f32x4*)(bptr[p]));
  }
  __syncthreads();

  int cur = 0;
  for (int kt = 0; kt < DIN / BK; ++kt) {
    f32x4 ra[4], rb[4];
    const bool more = (kt + 1 < DIN / BK);
    if (more) {
      const int koff = (kt + 1) * BK;
      #pragma unroll
      for (int p = 0; p < 4; ++p) {
        ra[p] = *(const f32x4*)(aptr[p] + koff);
        rb[p] = *(const f32x4*)(bptr[p] + koff);
      }
    }
    bf16x8 af[4], bfr[4];
    #pragma unroll
    for (int m = 0; m < 4; ++m)
      af[m] = *(const bf16x8*)&fA[cur][(wr + m * 16 + lr) * LDSK + lk * 8];
    #pragma unroll
    for (int n = 0; n < 4; ++n)
      bfr[n] = *(const bf16x8*)&fB[cur][(wc + n * 16 + lr) * LDSK + lk * 8];
    #pragma unroll
    for (int m = 0; m < 4; ++m)
      #pragma unroll
      for (int n = 0; n < 4; ++n)
        accf[m][n] = __builtin_amdgcn_mfma_f32_16x16x32_bf16(af[m], bfr[n], accf[m][n], 0, 0, 0);
    if (more) {
      #pragma unroll
      for (int p = 0; p < 4; ++p) {
        int r = p * 32 + srow;
        *(unsigned long long*)&fA[cur ^ 1][r * LDSK + scol] = pack4(ra[p]);
        *(unsigned long long*)&fB[cur ^ 1][r * LDSK + scol] = pack4(rb[p]);
      }
    }
    __syncthreads();
    cur ^= 1;
  }

  float bias[4];
  #pragma unroll
  for (int n = 0; n < 4; ++n) bias[n] = eb[e * DOUT + n0 + wc + n * 16 + lr];

  #pragma unroll
  for (int m = 0; m < 4; ++m) {
    #pragma unroll
    for (int j = 0; j < 4; ++j) {
      int rloc = wr + m * 16 + lk * 4 + j;
      if (m0 + rloc < Me) {
        int tokr = rowtok[rloc];
        float* op = out + (size_t)tokr * DOUT + n0 + wc;
        #pragma unroll
        for (int n = 0; n < 4; ++n)
          op[n * 16 + lr] = accf[m][n][j] + bias[n];
      }
    }
  }
}

extern "C" void kernel_launch(void* const* d_in, const int* in_sizes, int n_in,
                              void* d_out, int out_size, void* d_ws, size_t ws_size,
                              hipStream_t stream) {
  const float* x  = (const float*)d_in[0];
  const float* gw = (const float*)d_in[1];
  const float* gb = (const float*)d_in[2];
  const float* ew = (const float*)d_in[3];
  const float* eb = (const float*)d_in[4];
  float* out = (float*)d_out;

  // ws layout: counts[16] | tlist[8*8192] | @1MB xbf (64MB) | wbf (256MB)
  int* counts = (int*)d_ws;
  int* tlist  = counts + 16;
  const size_t XOFF = 1u << 20;
  const size_t WOFF = XOFF + (size_t)TOK * DIN * 2;
  const size_t NEED = WOFF + (size_t)NE * DOUT * DIN * 2;

  hipMemsetAsync(counts, 0, 16 * sizeof(int), stream);

  if (ws_size >= NEED) {
    unsigned short* xbf = (unsigned short*)((char*)d_ws + XOFF);
    unsigned short* wbf = (unsigned short*)((char*)d_ws + WOFF);
    prep_kernel<<<TOK / 4 + 8192, 256, 0, stream>>>(x, gw, gb, counts, tlist, xbf, ew, wbf);
    // 1D grid: 72 slots x 32 ntiles = 2304 blocks (8 | 2304), XCD-chunked in-kernel
    moe_gemm_bf<<<(TOK / BM + NE) * (DOUT / BN), 256, 0, stream>>>(xbf, wbf, eb, counts, tlist, out);
  } else {
    gate_kernel<<<TOK / 4, 256, 0, stream>>>(x, gw, gb, counts, tlist);
    dim3 grid(DOUT / BM, TOK / BM + NE, 1);
    moe_gemm<<<grid, 256, 0, stream>>>(x, ew, eb, counts, tlist, out);
  }
}

// Round 13
// 573.683 us; speedup vs baseline: 1.1229x; 1.1229x over previous
//
#include <hip/hip_runtime.h>

#define NE   8
#define DIN  4096
#define DOUT 4096
#define TOK  8192

#define BM 128
#define BN 128
#define BKF 64    // fast-path K-step (bf16 elems)

// legacy fallback tile params
#define BK 32
#define LDSK 40

typedef __attribute__((ext_vector_type(4))) float f32x4;
typedef __attribute__((ext_vector_type(8))) short bf16x8;
typedef __attribute__((ext_vector_type(2))) unsigned long long u64x2;

#define AS1 __attribute__((address_space(1)))
#define AS3 __attribute__((address_space(3)))

static __device__ __forceinline__ unsigned short f2bf(float f) {
  unsigned u = __builtin_bit_cast(unsigned, f);
  u += 0x7fffu + ((u >> 16) & 1u);   // RTNE
  return (unsigned short)(u >> 16);
}

static __device__ __forceinline__ unsigned long long pack4(f32x4 v) {
  return (unsigned long long)f2bf(v[0])
       | ((unsigned long long)f2bf(v[1]) << 16)
       | ((unsigned long long)f2bf(v[2]) << 32)
       | ((unsigned long long)f2bf(v[3]) << 48);
}

static __device__ __forceinline__ void gload16(const void* g, void* l) {
  __builtin_amdgcn_global_load_lds((const AS1 unsigned int*)g,
                                   (AS3 unsigned int*)l, 16, 0, 0);
}

// ---------- fused prep: gating (fp32-exact) + x->bf16  AND  weights->bf16 ----------
__global__ void prep_kernel(const float* __restrict__ x, const float* __restrict__ gw,
                            const float* __restrict__ gb, int* __restrict__ counts,
                            int* __restrict__ tlist, unsigned short* __restrict__ xbf,
                            const float* __restrict__ ew, unsigned short* __restrict__ wbf) {
  if (blockIdx.x < TOK / 4) {
    // ---- gating + x conversion (4 tokens/block, 1 wave/token) ----
    const int lane = threadIdx.x & 63;
    const int tok  = blockIdx.x * 4 + (threadIdx.x >> 6);
    const float* xr = x + (size_t)tok * DIN;
    unsigned short* xo = xbf + (size_t)tok * DIN;
    float acc[NE];
    #pragma unroll
    for (int e = 0; e < NE; ++e) acc[e] = 0.f;
    for (int i = lane * 4; i < DIN; i += 256) {
      f32x4 xv = *(const f32x4*)(xr + i);
      *(unsigned long long*)(xo + i) = pack4(xv);
      #pragma unroll
      for (int e = 0; e < NE; ++e) {
        f32x4 wv = *(const f32x4*)(gw + e * DIN + i);
        acc[e] += xv[0]*wv[0] + xv[1]*wv[1] + xv[2]*wv[2] + xv[3]*wv[3];
      }
    }
    #pragma unroll
    for (int e = 0; e < NE; ++e) {
      float v = acc[e];
      #pragma unroll
      for (int o = 32; o > 0; o >>= 1) v += __shfl_xor(v, o);
      acc[e] = v;
    }
    if (lane == 0) {
      float bv = acc[0] + gb[0];
      int best = 0;
      #pragma unroll
      for (int e = 1; e < NE; ++e) {
        float v = acc[e] + gb[e];
        if (v > bv) { bv = v; best = e; }   // strict > == numpy first-max
      }
      int pos = atomicAdd(&counts[best], 1);
      tlist[best * TOK + pos] = tok;
    }
  } else {
    // ---- expert weights fp32 -> bf16 (8192 blocks, grid-stride) ----
    const int bid = blockIdx.x - TOK / 4;
    const size_t n = (size_t)NE * DOUT * DIN;
    size_t idx = ((size_t)bid * 256 + threadIdx.x) * 8;
    const size_t stride = (size_t)8192 * 256 * 8;
    for (; idx < n; idx += stride) {
      f32x4 a = *(const f32x4*)(ew + idx);
      f32x4 b = *(const f32x4*)(ew + idx + 4);
      u64x2 v; v[0] = pack4(a); v[1] = pack4(b);
      *(u64x2*)(wbf + idx) = v;
    }
  }
}

// ---------- fast grouped GEMM (round-7 proven optimum, verbatim) ----------
// 128x128, BK=64, single-buffer 2-barrier loop, global_load_lds width-16,
// pre-swizzled source: 341 us, MfmaUtil 37%, bank conflicts == 0.
// Default 2D dispatch (ntile = blockIdx.x fastest) keeps all 32 ntiles of a
// slot concurrent -> A-panel + expert weight panel shared in L3 by all
// concurrent blocks (XCD-chunked remap measured WORSE in r12: +30% FETCH).
__global__ __launch_bounds__(256, 2)
void moe_gemm_bf(const unsigned short* __restrict__ xbf,
                 const unsigned short* __restrict__ wbf,
                 const float* __restrict__ eb,
                 const int* __restrict__ counts,
                 const int* __restrict__ tlist,
                 float* __restrict__ out) {
  __shared__ unsigned short sA[BM * BKF];  // 16 KB, linear [128][64]
  __shared__ unsigned short sB[BN * BKF];  // 16 KB
  __shared__ int rowtok[BM];

  const int tid  = threadIdx.x;
  const int slot = blockIdx.y;

  int e = -1, mtile = 0, Me = 0;
  {
    int acc = 0;
    #pragma unroll
    for (int j = 0; j < NE; ++j) {
      int c = counts[j];
      int t = (c + BM - 1) / BM;
      if (e < 0 && slot < acc + t) { e = j; mtile = slot - acc; Me = c; }
      acc += t;
    }
  }
  if (e < 0) return;

  const int n0 = blockIdx.x * BN;
  const int m0 = mtile * BM;

  if (tid < BM) {
    int r = m0 + tid;
    rowtok[tid] = tlist[e * TOK + (r < Me ? r : Me - 1)];
  }
  __syncthreads();

  const int lane = tid & 63;
  const int w    = tid >> 6;
  // staging geometry: each wave chunk c stages 8 rows x 64 cols (1 KB)
  const int j8   = lane & 7;     // 16B slot within row
  const int rsub = lane >> 3;    // row within 8-row chunk
  const int colsw = ((j8 ^ rsub) * 8);  // pre-swizzled global elem offset (T2 involution)

  const unsigned short* ag[4];
  const unsigned short* bg[4];
  const unsigned short* wbase = wbf + (size_t)e * DOUT * DIN;
  #pragma unroll
  for (int c = 0; c < 4; ++c) {
    int row = (w * 4 + c) * 8 + rsub;
    ag[c] = xbf   + (size_t)rowtok[row] * DIN + colsw;
    bg[c] = wbase + (size_t)(n0 + row)  * DIN + colsw;
  }

  const int wr = (w >> 1) * 64;
  const int wc = (w & 1) * 64;
  const int lr = lane & 15;
  const int lk = lane >> 4;
  const int lr7 = lr & 7;

  f32x4 acc[4][4];
  #pragma unroll
  for (int m = 0; m < 4; ++m)
    #pragma unroll
    for (int n = 0; n < 4; ++n) acc[m][n] = (f32x4){0.f, 0.f, 0.f, 0.f};

  for (int kt = 0; kt < DIN / BKF; ++kt) {   // 64 K-tiles
    const int kofs = kt * BKF;
    #pragma unroll
    for (int c = 0; c < 4; ++c) {
      gload16(ag[c] + kofs, &sA[(w * 4 + c) * 512]);
      gload16(bg[c] + kofs, &sB[(w * 4 + c) * 512]);
    }
    __syncthreads();   // drains vmcnt before barrier (compiler-inserted)

    #pragma unroll
    for (int ks = 0; ks < 2; ++ks) {
      bf16x8 af[4], bfv[4];
      #pragma unroll
      for (int m = 0; m < 4; ++m)
        af[m] = *(const bf16x8*)&sA[(wr + m * 16 + lr) * BKF + (((ks * 4 + lk) ^ lr7) * 8)];
      #pragma unroll
      for (int n = 0; n < 4; ++n)
        bfv[n] = *(const bf16x8*)&sB[(wc + n * 16 + lr) * BKF + (((ks * 4 + lk) ^ lr7) * 8)];
      #pragma unroll
      for (int m = 0; m < 4; ++m)
        #pragma unroll
        for (int n = 0; n < 4; ++n)
          acc[m][n] = __builtin_amdgcn_mfma_f32_16x16x32_bf16(af[m], bfv[n], acc[m][n], 0, 0, 0);
    }
    __syncthreads();
  }

  // epilogue: bias + guarded scatter (C/D: col = lane&15, row = (lane>>4)*4 + j)
  float bias[4];
  #pragma unroll
  for (int n = 0; n < 4; ++n) bias[n] = eb[e * DOUT + n0 + wc + n * 16 + lr];

  #pragma unroll
  for (int m = 0; m < 4; ++m) {
    #pragma unroll
    for (int j = 0; j < 4; ++j) {
      int rloc = wr + m * 16 + lk * 4 + j;
      if (m0 + rloc < Me) {
        int tokr = rowtok[rloc];
        float* op = out + (size_t)tokr * DOUT + n0 + wc;
        #pragma unroll
        for (int n = 0; n < 4; ++n)
          op[n * 16 + lr] = acc[m][n][j] + bias[n];
      }
    }
  }
}

// ================= legacy fallback path (used only if ws too small) ==========
__global__ void gate_kernel(const float* __restrict__ x, const float* __restrict__ gw,
                            const float* __restrict__ gb, int* __restrict__ counts,
                            int* __restrict__ tlist) {
  const int lane = threadIdx.x & 63;
  const int tok  = blockIdx.x * 4 + (threadIdx.x >> 6);
  const float* xr = x + (size_t)tok * DIN;
  float acc[NE];
  #pragma unroll
  for (int e = 0; e < NE; ++e) acc[e] = 0.f;
  for (int i = lane; i < DIN; i += 64) {
    float xv = xr[i];
    #pragma unroll
    for (int e = 0; e < NE; ++e) acc[e] += xv * gw[e * DIN + i];
  }
  #pragma unroll
  for (int e = 0; e < NE; ++e) {
    float v = acc[e];
    #pragma unroll
    for (int o = 32; o > 0; o >>= 1) v += __shfl_xor(v, o);
    acc[e] = v;
  }
  if (lane == 0) {
    float bv = acc[0] + gb[0];
    int best = 0;
    #pragma unroll
    for (int e = 1; e < NE; ++e) {
      float v = acc[e] + gb[e];
      if (v > bv) { bv = v; best = e; }
    }
    int pos = atomicAdd(&counts[best], 1);
    tlist[best * TOK + pos] = tok;
  }
}

__global__ __launch_bounds__(256, 2)
void moe_gemm(const float* __restrict__ x, const float* __restrict__ ew,
              const float* __restrict__ eb, const int* __restrict__ counts,
              const int* __restrict__ tlist, float* __restrict__ out) {
  __shared__ unsigned short fA[2][BM * LDSK];
  __shared__ unsigned short fB[2][BM * LDSK];
  __shared__ int rowtok[BM];

  const int tid  = threadIdx.x;
  const int slot = blockIdx.y;

  int e = -1, mtile = 0, Me = 0;
  {
    int acc = 0;
    #pragma unroll
    for (int j = 0; j < NE; ++j) {
      int c = counts[j];
      int t = (c + BM - 1) / BM;
      if (e < 0 && slot < acc + t) { e = j; mtile = slot - acc; Me = c; }
      acc += t;
    }
  }
  if (e < 0) return;

  const int n0 = blockIdx.x * BM;
  const int m0 = mtile * BM;
  const float* we = ew + (size_t)e * DOUT * DIN;

  if (tid < BM) {
    int r = m0 + tid;
    rowtok[tid] = tlist[e * TOK + (r < Me ? r : Me - 1)];
  }
  __syncthreads();

  const int srow = tid >> 3;
  const int scol = (tid & 7) * 4;
  const int lane = tid & 63;
  const int w  = tid >> 6;
  const int wr = (w >> 1) * 64;
  const int wc = (w & 1) * 64;
  const int lr = lane & 15;
  const int lk = lane >> 4;

  f32x4 accf[4][4];
  #pragma unroll
  for (int m = 0; m < 4; ++m)
    #pragma unroll
    for (int n = 0; n < 4; ++n) accf[m][n] = (f32x4){0.f, 0.f, 0.f, 0.f};

  const float* aptr[4];
  const float* bptr[4];
  #pragma unroll
  for (int p = 0; p < 4; ++p) {
    int r = p * 32 + srow;
    aptr[p] = x  + (size_t)rowtok[r] * DIN + scol;
    bptr[p] = we + (size_t)(n0 + r)  * DIN + scol;
  }

  #pragma unroll
  for (int p = 0; p < 4; ++p) {
    int r = p * 32 + srow;
    *(unsigned long long*)&fA[0][r * LDSK + scol] = pack4(*(const f32x4*)(aptr[p]));
    *(unsigned long long*)&fB[0][r * LDSK + scol] = pack4(*(const f32x4*)(bptr[p]));
  }
  __syncthreads();

  int cur = 0;
  for (int kt = 0; kt < DIN / BK; ++kt) {
    f32x4 ra[4], rb[4];
    const bool more = (kt + 1 < DIN / BK);
    if (more) {
      const int koff = (kt + 1) * BK;
      #pragma unroll
      for (int p = 0; p < 4; ++p) {
        ra[p] = *(const f32x4*)(aptr[p] + koff);
        rb[p] = *(const f32x4*)(bptr[p] + koff);
      }
    }
    bf16x8 af[4], bfr[4];
    #pragma unroll
    for (int m = 0; m < 4; ++m)
      af[m] = *(const bf16x8*)&fA[cur][(wr + m * 16 + lr) * LDSK + lk * 8];
    #pragma unroll
    for (int n = 0; n < 4; ++n)
      bfr[n] = *(const bf16x8*)&fB[cur][(wc + n * 16 + lr) * LDSK + lk * 8];
    #pragma unroll
    for (int m = 0; m < 4; ++m)
      #pragma unroll
      for (int n = 0; n < 4; ++n)
        accf[m][n] = __builtin_amdgcn_mfma_f32_16x16x32_bf16(af[m], bfr[n], accf[m][n], 0, 0, 0);
    if (more) {
      #pragma unroll
      for (int p = 0; p < 4; ++p) {
        int r = p * 32 + srow;
        *(unsigned long long*)&fA[cur ^ 1][r * LDSK + scol] = pack4(ra[p]);
        *(unsigned long long*)&fB[cur ^ 1][r * LDSK + scol] = pack4(rb[p]);
      }
    }
    __syncthreads();
    cur ^= 1;
  }

  float bias[4];
  #pragma unroll
  for (int n = 0; n < 4; ++n) bias[n] = eb[e * DOUT + n0 + wc + n * 16 + lr];

  #pragma unroll
  for (int m = 0; m < 4; ++m) {
    #pragma unroll
    for (int j = 0; j < 4; ++j) {
      int rloc = wr + m * 16 + lk * 4 + j;
      if (m0 + rloc < Me) {
        int tokr = rowtok[rloc];
        float* op = out + (size_t)tokr * DOUT + n0 + wc;
        #pragma unroll
        for (int n = 0; n < 4; ++n)
          op[n * 16 + lr] = accf[m][n][j] + bias[n];
      }
    }
  }
}

extern "C" void kernel_launch(void* const* d_in, const int* in_sizes, int n_in,
                              void* d_out, int out_size, void* d_ws, size_t ws_size,
                              hipStream_t stream) {
  const float* x  = (const float*)d_in[0];
  const float* gw = (const float*)d_in[1];
  const float* gb = (const float*)d_in[2];
  const float* ew = (const float*)d_in[3];
  const float* eb = (const float*)d_in[4];
  float* out = (float*)d_out;

  // ws layout: counts[16] | tlist[8*8192] | @1MB xbf (64MB) | wbf (256MB)
  int* counts = (int*)d_ws;
  int* tlist  = counts + 16;
  const size_t XOFF = 1u << 20;
  const size_t WOFF = XOFF + (size_t)TOK * DIN * 2;
  const size_t NEED = WOFF + (size_t)NE * DOUT * DIN * 2;

  hipMemsetAsync(counts, 0, 16 * sizeof(int), stream);

  if (ws_size >= NEED) {
    unsigned short* xbf = (unsigned short*)((char*)d_ws + XOFF);
    unsigned short* wbf = (unsigned short*)((char*)d_ws + WOFF);
    prep_kernel<<<TOK / 4 + 8192, 256, 0, stream>>>(x, gw, gb, counts, tlist, xbf, ew, wbf);
    dim3 grid(DOUT / BN, TOK / BM + NE, 1);   // 32 n-tiles x 72 worst-case m-slots
    moe_gemm_bf<<<grid, 256, 0, stream>>>(xbf, wbf, eb, counts, tlist, out);
  } else {
    gate_kernel<<<TOK / 4, 256, 0, stream>>>(x, gw, gb, counts, tlist);
    dim3 grid(DOUT / BM, TOK / BM + NE, 1);
    moe_gemm<<<grid, 256, 0, stream>>>(x, ew, eb, counts, tlist, out);
  }
}